// Round 16
// baseline (141.582 us; speedup 1.0000x reference)
//
#include <hip/hip_runtime.h>
#include <stdint.h>

#define LOG2G -0.045803689611862786f   // log2(0.96875)

typedef float f32x4 __attribute__((ext_vector_type(4)));
typedef short bf16x8 __attribute__((ext_vector_type(8)));

__device__ inline unsigned short f2bf(float f) {
  uint32_t u = __builtin_bit_cast(uint32_t, f);
  u += 0x7FFFu + ((u >> 16) & 1u);     // RNE
  return (unsigned short)(u >> 16);
}
__device__ inline float b2f(unsigned short u) {
  return __builtin_bit_cast(float, (uint32_t)u << 16);
}

#if __has_builtin(__builtin_amdgcn_global_load_lds)
#define USE_GLL 1
#endif

// Stage one 1KB row (512 bf16) of global into LDS. Lane l covers granule l (16B).
__device__ __forceinline__ void stage_row(const unsigned short* __restrict__ srcrow,
                                          unsigned short* ldsrow, int lane, int swz) {
#ifdef USE_GLL
  __builtin_amdgcn_global_load_lds(
      (const __attribute__((address_space(1))) uint32_t*)((const char*)srcrow + ((lane ^ swz) << 4)),
      (__attribute__((address_space(3))) uint32_t*)ldsrow, 16, 0, 0);
#else
  bf16x8 v = *(const bf16x8*)((const char*)srcrow + ((lane ^ swz) << 4));
  *(bf16x8*)((char*)ldsrow + (lane << 4)) = v;
#endif
}

// ---------------- Stage 0a: transpose W -> Wt[n][k] bf16 ----------------
__global__ __launch_bounds__(256) void prep_kernel(
    const float* __restrict__ wq, const float* __restrict__ wk,
    const float* __restrict__ wv, unsigned short* __restrict__ Wt)
{
  __shared__ unsigned short lh[64][68];
  const int blk = blockIdx.x;
  const int w3 = blk >> 6;
  const int tile = blk & 63;
  const int tk = (tile >> 3) * 64, tn = (tile & 7) * 64;
  const float* W = (w3 == 0) ? wq : ((w3 == 1) ? wk : wv);
  const int t = threadIdx.x;
  {
    const int kl = t >> 2, nq = (t & 3) * 16;
#pragma unroll
    for (int f = 0; f < 4; ++f) {
      float4 v = *(const float4*)&W[(size_t)(tk + kl) * 512 + tn + nq + f * 4];
      float vv[4] = {v.x, v.y, v.z, v.w};
      ushort4 h4;
#pragma unroll
      for (int e = 0; e < 4; ++e) ((unsigned short*)&h4)[e] = f2bf(vv[e]);
      *(ushort4*)&lh[kl][nq + f * 4] = h4;
    }
  }
  __syncthreads();
  {
    const int nl = t >> 2, kq = (t & 3) * 16;
    unsigned short* outh = Wt + (size_t)w3 * 262144 + (size_t)(tn + nl) * 512 + tk + kq;
#pragma unroll
    for (int f = 0; f < 4; ++f) {
      ushort4 h4;
#pragma unroll
      for (int e = 0; e < 4; ++e) ((unsigned short*)&h4)[e] = lh[kq + f * 4 + e][nl];
      *(ushort4*)&outh[f * 4] = h4;
    }
  }
}

// ---------------- Stage 0b: x fp32 -> bf16 ----------------
__global__ __launch_bounds__(256) void xconv_kernel(
    const float* __restrict__ x, unsigned short* __restrict__ xb)
{
  const size_t i = ((size_t)blockIdx.x * 256 + threadIdx.x) * 8;
  float4 v0 = *(const float4*)&x[i];
  float4 v1 = *(const float4*)&x[i + 4];
  bf16x8 o;
  o[0] = (short)f2bf(v0.x); o[1] = (short)f2bf(v0.y);
  o[2] = (short)f2bf(v0.z); o[3] = (short)f2bf(v0.w);
  o[4] = (short)f2bf(v1.x); o[5] = (short)f2bf(v1.y);
  o[6] = (short)f2bf(v1.z); o[7] = (short)f2bf(v1.w);
  *(bf16x8*)&xb[i] = o;
}

// ---------------- Stage 1: LDS-staged MFMA projections (z-merged) ----------------
__global__ __launch_bounds__(256) void proj_kernel(
    const unsigned short* __restrict__ xb, const unsigned short* __restrict__ Wt,
    const float* __restrict__ theta,
    unsigned short* __restrict__ Qc, unsigned short* __restrict__ Qs,
    unsigned short* __restrict__ Kc, unsigned short* __restrict__ Ks,
    unsigned short* __restrict__ Vt)
{
  __shared__ unsigned short Al[64 * 512];   // 64 KB
  __shared__ unsigned short Bl[64 * 512];   // 64 KB
  __shared__ unsigned short T[64][136];     // 17.4 KB
  const int tid = threadIdx.x;
  const int wave = tid >> 6, lane = tid & 63;
  const int r = lane & 15, g = lane >> 4;
  const int wm = wave >> 1, wn = wave & 1;
  const int nbase = blockIdx.x * 64, mbase = blockIdx.y * 64;

#pragma unroll
  for (int i = 0; i < 16; ++i) {
    const int row = wave * 16 + i;
    stage_row(xb + (size_t)(mbase + row) * 512, &Al[row * 512], lane, row & 7);
  }
#pragma unroll
  for (int i = 0; i < 16; ++i) {
    const int row = wave * 16 + i;
    stage_row(Wt + (size_t)(nbase + row) * 512, &Bl[row * 512], lane, row & 7);
  }

  float C1[2], S1[2], CZ[2], SZ[2], C16[2], S16[2];
  const int pos0 = (mbase & 2047) + wm * 32 + g * 4;
#pragma unroll
  for (int nf = 0; nf < 2; ++nf) {
    const float th = theta[nbase + wn * 32 + nf * 16 + r];
    float c1, s1, cz, sz;
    sincosf(th, &s1, &c1);
    sincosf((float)(pos0 + 1) * th, &sz, &cz);
    float c2 = c1 * c1 - s1 * s1, s2 = 2.f * c1 * s1;
    float c4 = c2 * c2 - s2 * s2, s4 = 2.f * c2 * s2;
    float c8 = c4 * c4 - s4 * s4, s8 = 2.f * c4 * s4;
    C1[nf] = c1; S1[nf] = s1; CZ[nf] = cz; SZ[nf] = sz;
    C16[nf] = c8 * c8 - s8 * s8; S16[nf] = 2.f * c8 * s8;
  }
  __syncthreads();

#pragma unroll
  for (int z = 0; z < 3; ++z) {
    f32x4 acc[2][2];
#pragma unroll
    for (int mf = 0; mf < 2; ++mf)
#pragma unroll
      for (int nf = 0; nf < 2; ++nf) acc[mf][nf] = (f32x4){0.f, 0.f, 0.f, 0.f};
#pragma unroll
    for (int ks = 0; ks < 16; ++ks) {
      const int off = (((ks * 4) + g) ^ (r & 7)) << 3;
      bf16x8 a0 = *(const bf16x8*)&Al[(wm * 32 + r) * 512 + off];
      bf16x8 a1 = *(const bf16x8*)&Al[(wm * 32 + 16 + r) * 512 + off];
      bf16x8 b0 = *(const bf16x8*)&Bl[(wn * 32 + r) * 512 + off];
      bf16x8 b1 = *(const bf16x8*)&Bl[(wn * 32 + 16 + r) * 512 + off];
      acc[0][0] = __builtin_amdgcn_mfma_f32_16x16x32_bf16(a0, b0, acc[0][0], 0, 0, 0);
      acc[0][1] = __builtin_amdgcn_mfma_f32_16x16x32_bf16(a0, b1, acc[0][1], 0, 0, 0);
      acc[1][0] = __builtin_amdgcn_mfma_f32_16x16x32_bf16(a1, b0, acc[1][0], 0, 0, 0);
      acc[1][1] = __builtin_amdgcn_mfma_f32_16x16x32_bf16(a1, b1, acc[1][1], 0, 0, 0);
    }
    __syncthreads();

    if (z < 2) {
#pragma unroll
      for (int i = 0; i < 16; ++i) {
        const int row = wave * 16 + i;
        stage_row(Wt + (size_t)(z + 1) * 262144 + (size_t)(nbase + row) * 512,
                  &Bl[row * 512], lane, row & 7);
      }
    }

    if (z == 2) {
#pragma unroll
      for (int nf = 0; nf < 2; ++nf) {
        const int nl = wn * 32 + nf * 16 + r;
#pragma unroll
        for (int mf = 0; mf < 2; ++mf)
#pragma unroll
          for (int i = 0; i < 4; ++i)
            T[nl][wm * 32 + mf * 16 + g * 4 + i] = f2bf(acc[mf][nf][i]);
      }
      __syncthreads();
      const int bb = mbase >> 11, posb = mbase & 2047;
#pragma unroll
      for (int p = 0; p < 2; ++p) {
        const int row = p * 32 + (tid >> 3);
        bf16x8 v = *(const bf16x8*)&T[row][(tid & 7) * 8];
        *(bf16x8*)&Vt[((size_t)bb * 512 + nbase + row) * 2048 + posb + (tid & 7) * 8] = v;
      }
    } else {
#pragma unroll
      for (int pl = 0; pl < 2; ++pl) {
        if (pl) __syncthreads();
#pragma unroll
        for (int nf = 0; nf < 2; ++nf) {
          const int nl = wn * 32 + nf * 16 + r;
          float cz = CZ[nf], sz = SZ[nf];
          const float c1 = C1[nf], s1 = S1[nf], c16 = C16[nf], s16 = S16[nf];
#pragma unroll
          for (int mf = 0; mf < 2; ++mf) {
            float cc = cz, ss = sz;
#pragma unroll
            for (int i = 0; i < 4; ++i) {
              const float f = pl ? ss : cc;
              T[wm * 32 + mf * 16 + g * 4 + i][nl] = f2bf(acc[mf][nf][i] * f);
              float nc = cc * c1 - ss * s1, ns = cc * s1 + ss * c1;
              cc = nc; ss = ns;
            }
            float zc = cz * c16 - sz * s16, zs = cz * s16 + sz * c16;
            cz = zc; sz = zs;
          }
        }
        __syncthreads();
        unsigned short* dst = (z == 0) ? (pl ? Qs : Qc) : (pl ? Ks : Kc);
#pragma unroll
        for (int p = 0; p < 2; ++p) {
          const int row = p * 32 + (tid >> 3);
          bf16x8 v = *(const bf16x8*)&T[row][(tid & 7) * 8];
          *(bf16x8*)&dst[(size_t)(mbase + row) * 512 + nbase + (tid & 7) * 8] = v;
        }
      }
      __syncthreads();
    }
  }
}

// ---------------- Stage 2: retention, QBLK=32, 8 waves, decay-banded (W=256) --------
// Waves: wm = w&3 (m-frag), wq2 = w>>2 (q-group). One Klds tile feeds 32 q rows.
// 256 blocks = 1/CU (single round). Output pack (verified): im | re<<16.
__global__ __launch_bounds__(512, 1) void ret_kernel(
    const unsigned short* __restrict__ Qc, const unsigned short* __restrict__ Qs,
    const unsigned short* __restrict__ Kc, const unsigned short* __restrict__ Ks,
    const unsigned short* __restrict__ Vt, uint32_t* __restrict__ out)
{
  __shared__ unsigned short Klds[128 * 512];   // rows 0-63: Kc, 64-127: Ks (swz granules)
  __shared__ unsigned short Prl[2][16 * 72];
  __shared__ unsigned short Pil[2][16 * 72];

  const int bid = blockIdx.x;
  const int sid = ((bid & 7) << 5) + (bid >> 3);  // XCD chunk swizzle (bijective, 256=8*32)
  const int b = sid >> 6;
  const int qblk = 63 - (sid & 63);               // heavy-first
  const int q0 = qblk * 32;
  const int tid = threadIdx.x;
  const int wave = tid >> 6;
  const int lane = tid & 63;
  const int r = lane & 15;
  const int g = lane >> 4;
  const int wm = wave & 3;
  const int wq2 = wave >> 2;
  const int sw = r & 7;

  // ---- Q-frags: this wave's 16 q rows (q-group wq2) x 512h (c & s) ----
  bf16x8 qa[16], qb[16];
  {
    const unsigned short* qcr = Qc + ((size_t)b * 2048 + q0 + wq2 * 16 + r) * 512 + g * 8;
    const unsigned short* qsr = Qs + ((size_t)b * 2048 + q0 + wq2 * 16 + r) * 512 + g * 8;
#pragma unroll
    for (int ks = 0; ks < 16; ++ks) {
      qa[ks] = *(const bf16x8*)(qcr + ks * 32);
      qb[ks] = *(const bf16x8*)(qsr + ks * 32);
    }
  }

  const int ntiles = ((q0 + 31) >> 6) + 1;
  const int t0 = (q0 >= 256) ? ((q0 - 256) >> 6) : 0;   // decay band start

  // ---- stage K(t0): 128 rows split across 8 waves ----
  {
    const size_t kbase = ((size_t)b * 2048 + (t0 << 6)) * 512;
#pragma unroll
    for (int i = 0; i < 16; ++i) {
      const int rid = wave * 16 + i;
      const int row = rid & 63;
      const unsigned short* src = ((rid < 64) ? Kc : Ks) + kbase + (size_t)row * 512;
      stage_row(src, &Klds[(size_t)rid * 512], lane, rid & 7);
    }
  }
  __syncthreads();

  f32x4 outre[2][4], outim[2][4];
#pragma unroll
  for (int qg = 0; qg < 2; ++qg)
#pragma unroll
    for (int c = 0; c < 4; ++c) {
      outre[qg][c] = (f32x4){0.f, 0.f, 0.f, 0.f};
      outim[qg][c] = (f32x4){0.f, 0.f, 0.f, 0.f};
    }

  for (int t = t0; t < ntiles; ++t) {
    const int m0 = t << 6;
    // ---- Phase A: QK from LDS (swizzled) + reg Q; this wave: m-frag wm, q-group wq2 ----
    f32x4 acc_cc = {0.f, 0.f, 0.f, 0.f};
    f32x4 acc_ss = {0.f, 0.f, 0.f, 0.f};
    f32x4 ai1 = {0.f, 0.f, 0.f, 0.f};
    f32x4 ai2 = {0.f, 0.f, 0.f, 0.f};
    const unsigned short* krow_c = &Klds[(wm * 16 + r) * 512];
    const unsigned short* krow_s = krow_c + 64 * 512;
#pragma unroll
    for (int ks = 0; ks < 16; ++ks) {
      const int off = (((ks * 4) + g) ^ sw) << 3;
      bf16x8 ka = *(const bf16x8*)(krow_c + off);
      bf16x8 kb = *(const bf16x8*)(krow_s + off);
      acc_cc = __builtin_amdgcn_mfma_f32_16x16x32_bf16(ka, qa[ks], acc_cc, 0, 0, 0);
      acc_ss = __builtin_amdgcn_mfma_f32_16x16x32_bf16(kb, qb[ks], acc_ss, 0, 0, 0);
      ai1    = __builtin_amdgcn_mfma_f32_16x16x32_bf16(ka, qb[ks], ai1, 0, 0, 0);
      ai2    = __builtin_amdgcn_mfma_f32_16x16x32_bf16(kb, qa[ks], ai2, 0, 0, 0);
    }
    // decay + pack P.  P^T layout per q-group: row m = wm*16 + g*4+rg, col q = r
    {
      const int qg_ = q0 + wq2 * 16 + r;
      const int mg = m0 + wm * 16 + g * 4;
#pragma unroll
      for (int rg = 0; rg < 4; ++rg) {
        int d = qg_ - (mg + rg);
        float wdec = (d >= 0) ? exp2f((float)d * LOG2G) : 0.0f;
        Prl[wq2][r * 72 + wm * 16 + g * 4 + rg] = f2bf((acc_cc[rg] + acc_ss[rg]) * wdec);
        Pil[wq2][r * 72 + wm * 16 + g * 4 + rg] = f2bf((ai1[rg] - ai2[rg]) * wdec);
      }
    }
    __syncthreads();   // P visible; all waves done reading K(t)

    // ---- V loads FIRST (h-slice of 64 per wave) ----
    const unsigned short* vtp =
        Vt + ((size_t)b * 512 + wave * 64 + r) * 2048 + m0 + g * 8;
    bf16x8 vv[4][2];
#pragma unroll
    for (int c = 0; c < 4; ++c)
#pragma unroll
      for (int k2 = 0; k2 < 2; ++k2)
        vv[c][k2] = *reinterpret_cast<const bf16x8*>(
            vtp + (size_t)c * 16 * 2048 + k2 * 32);

    // ---- issue K(t+1) staging (drains during PV) ----
    if (t + 1 < ntiles) {
      const size_t kbase = ((size_t)b * 2048 + m0 + 64) * 512;
#pragma unroll
      for (int i = 0; i < 16; ++i) {
        const int rid = wave * 16 + i;
        const int row = rid & 63;
        const unsigned short* src = ((rid < 64) ? Kc : Ks) + kbase + (size_t)row * 512;
        stage_row(src, &Klds[(size_t)rid * 512], lane, rid & 7);
      }
    }

    // ---- Phase B: out += P @ V for both q-groups ----
#pragma unroll
    for (int qg = 0; qg < 2; ++qg) {
      bf16x8 pr[2], pi[2];
#pragma unroll
      for (int k2 = 0; k2 < 2; ++k2) {
        pr[k2] = *reinterpret_cast<const bf16x8*>(&Prl[qg][r * 72 + k2 * 32 + g * 8]);
        pi[k2] = *reinterpret_cast<const bf16x8*>(&Pil[qg][r * 72 + k2 * 32 + g * 8]);
      }
#pragma unroll
      for (int c = 0; c < 4; ++c)
#pragma unroll
        for (int k2 = 0; k2 < 2; ++k2) {
          outre[qg][c] = __builtin_amdgcn_mfma_f32_16x16x32_bf16(pr[k2], vv[c][k2], outre[qg][c], 0, 0, 0);
          outim[qg][c] = __builtin_amdgcn_mfma_f32_16x16x32_bf16(pi[k2], vv[c][k2], outim[qg][c], 0, 0, 0);
        }
    }
    __syncthreads();   // drains staging (vmcnt 0) + P reuse safe
  }

  // epilogue: row q = q0 + qg*16 + g*4+rg, col h = wave*64 + c*16 + r; pack im|re<<16
#pragma unroll
  for (int qg = 0; qg < 2; ++qg)
#pragma unroll
    for (int c = 0; c < 4; ++c)
#pragma unroll
      for (int rg = 0; rg < 4; ++rg) {
        const int q = q0 + qg * 16 + g * 4 + rg;
        const int h = wave * 64 + c * 16 + r;
        const size_t o = ((size_t)b * 2048 + q) * 512 + h;
        out[o] = (uint32_t)f2bf(outim[qg][c][rg]) | ((uint32_t)f2bf(outre[qg][c][rg]) << 16);
      }
}

extern "C" void kernel_launch(void* const* d_in, const int* in_sizes, int n_in,
                              void* d_out, int out_size, void* d_ws, size_t ws_size,
                              hipStream_t stream) {
  (void)in_sizes; (void)n_in; (void)out_size; (void)ws_size;
  const float* x     = (const float*)d_in[0];
  const float* wq    = (const float*)d_in[1];
  const float* wk    = (const float*)d_in[2];
  const float* wv    = (const float*)d_in[3];
  const float* theta = (const float*)d_in[4];

  const size_t NEL = (size_t)4 * 2048 * 512;   // elements per bf16 matrix
  unsigned short* Qc = (unsigned short*)d_ws;
  unsigned short* Qs = Qc + NEL;
  unsigned short* Kc = Qs + NEL;
  unsigned short* Ks = Kc + NEL;
  unsigned short* Vt = Ks + NEL;               // [B][H][S]
  // transient buffers in d_out (fully overwritten by ret_kernel afterwards)
  unsigned short* Wt = (unsigned short*)d_out;             // 1.5 MB
  unsigned short* xb = (unsigned short*)d_out + 2097152;   // 8.4 MB @ 4MB offset

  prep_kernel<<<192, 256, 0, stream>>>(wq, wk, wv, Wt);
  xconv_kernel<<<2048, 256, 0, stream>>>(x, xb);
  dim3 gp(8, 128);
  proj_kernel<<<gp, 256, 0, stream>>>(xb, Wt, theta, Qc, Qs, Kc, Ks, Vt);
  ret_kernel<<<256, 512, 0, stream>>>(Qc, Qs, Kc, Ks, Vt, (uint32_t*)d_out);
}

// Round 17
// 140.846 us; speedup vs baseline: 1.0052x; 1.0052x over previous
//
#include <hip/hip_runtime.h>
#include <stdint.h>

#define LOG2G -0.045803689611862786f   // log2(0.96875)

typedef float f32x4 __attribute__((ext_vector_type(4)));
typedef short bf16x8 __attribute__((ext_vector_type(8)));

__device__ inline unsigned short f2bf(float f) {
  uint32_t u = __builtin_bit_cast(uint32_t, f);
  u += 0x7FFFu + ((u >> 16) & 1u);     // RNE
  return (unsigned short)(u >> 16);
}
__device__ inline float b2f(unsigned short u) {
  return __builtin_bit_cast(float, (uint32_t)u << 16);
}

#if __has_builtin(__builtin_amdgcn_global_load_lds)
#define USE_GLL 1
#endif

// Stage one 1KB row (512 bf16) of global into LDS. Lane l covers granule l (16B).
__device__ __forceinline__ void stage_row(const unsigned short* __restrict__ srcrow,
                                          unsigned short* ldsrow, int lane, int swz) {
#ifdef USE_GLL
  __builtin_amdgcn_global_load_lds(
      (const __attribute__((address_space(1))) uint32_t*)((const char*)srcrow + ((lane ^ swz) << 4)),
      (__attribute__((address_space(3))) uint32_t*)ldsrow, 16, 0, 0);
#else
  bf16x8 v = *(const bf16x8*)((const char*)srcrow + ((lane ^ swz) << 4));
  *(bf16x8*)((char*)ldsrow + (lane << 4)) = v;
#endif
}

// ---------------- Stage 0a: transpose W -> Wt[n][k] bf16 ----------------
__global__ __launch_bounds__(256) void prep_kernel(
    const float* __restrict__ wq, const float* __restrict__ wk,
    const float* __restrict__ wv, unsigned short* __restrict__ Wt)
{
  __shared__ unsigned short lh[64][68];
  const int blk = blockIdx.x;
  const int w3 = blk >> 6;
  const int tile = blk & 63;
  const int tk = (tile >> 3) * 64, tn = (tile & 7) * 64;
  const float* W = (w3 == 0) ? wq : ((w3 == 1) ? wk : wv);
  const int t = threadIdx.x;
  {
    const int kl = t >> 2, nq = (t & 3) * 16;
#pragma unroll
    for (int f = 0; f < 4; ++f) {
      float4 v = *(const float4*)&W[(size_t)(tk + kl) * 512 + tn + nq + f * 4];
      float vv[4] = {v.x, v.y, v.z, v.w};
      ushort4 h4;
#pragma unroll
      for (int e = 0; e < 4; ++e) ((unsigned short*)&h4)[e] = f2bf(vv[e]);
      *(ushort4*)&lh[kl][nq + f * 4] = h4;
    }
  }
  __syncthreads();
  {
    const int nl = t >> 2, kq = (t & 3) * 16;
    unsigned short* outh = Wt + (size_t)w3 * 262144 + (size_t)(tn + nl) * 512 + tk + kq;
#pragma unroll
    for (int f = 0; f < 4; ++f) {
      ushort4 h4;
#pragma unroll
      for (int e = 0; e < 4; ++e) ((unsigned short*)&h4)[e] = lh[kq + f * 4 + e][nl];
      *(ushort4*)&outh[f * 4] = h4;
    }
  }
}

// ---------------- Stage 0b: x fp32 -> bf16 ----------------
__global__ __launch_bounds__(256) void xconv_kernel(
    const float* __restrict__ x, unsigned short* __restrict__ xb)
{
  const size_t i = ((size_t)blockIdx.x * 256 + threadIdx.x) * 8;
  float4 v0 = *(const float4*)&x[i];
  float4 v1 = *(const float4*)&x[i + 4];
  bf16x8 o;
  o[0] = (short)f2bf(v0.x); o[1] = (short)f2bf(v0.y);
  o[2] = (short)f2bf(v0.z); o[3] = (short)f2bf(v0.w);
  o[4] = (short)f2bf(v1.x); o[5] = (short)f2bf(v1.y);
  o[6] = (short)f2bf(v1.z); o[7] = (short)f2bf(v1.w);
  *(bf16x8*)&xb[i] = o;
}

// ---------------- Stage 1: LDS-staged MFMA projections (z-merged) ----------------
__global__ __launch_bounds__(256) void proj_kernel(
    const unsigned short* __restrict__ xb, const unsigned short* __restrict__ Wt,
    const float* __restrict__ theta,
    unsigned short* __restrict__ Qc, unsigned short* __restrict__ Qs,
    unsigned short* __restrict__ Kc, unsigned short* __restrict__ Ks,
    unsigned short* __restrict__ Vt)
{
  __shared__ unsigned short Al[64 * 512];   // 64 KB
  __shared__ unsigned short Bl[64 * 512];   // 64 KB
  __shared__ unsigned short T[64][136];     // 17.4 KB
  const int tid = threadIdx.x;
  const int wave = tid >> 6, lane = tid & 63;
  const int r = lane & 15, g = lane >> 4;
  const int wm = wave >> 1, wn = wave & 1;
  const int nbase = blockIdx.x * 64, mbase = blockIdx.y * 64;

#pragma unroll
  for (int i = 0; i < 16; ++i) {
    const int row = wave * 16 + i;
    stage_row(xb + (size_t)(mbase + row) * 512, &Al[row * 512], lane, row & 7);
  }
#pragma unroll
  for (int i = 0; i < 16; ++i) {
    const int row = wave * 16 + i;
    stage_row(Wt + (size_t)(nbase + row) * 512, &Bl[row * 512], lane, row & 7);
  }

  float C1[2], S1[2], CZ[2], SZ[2], C16[2], S16[2];
  const int pos0 = (mbase & 2047) + wm * 32 + g * 4;
#pragma unroll
  for (int nf = 0; nf < 2; ++nf) {
    const float th = theta[nbase + wn * 32 + nf * 16 + r];
    float c1, s1, cz, sz;
    sincosf(th, &s1, &c1);
    sincosf((float)(pos0 + 1) * th, &sz, &cz);
    float c2 = c1 * c1 - s1 * s1, s2 = 2.f * c1 * s1;
    float c4 = c2 * c2 - s2 * s2, s4 = 2.f * c2 * s2;
    float c8 = c4 * c4 - s4 * s4, s8 = 2.f * c4 * s4;
    C1[nf] = c1; S1[nf] = s1; CZ[nf] = cz; SZ[nf] = sz;
    C16[nf] = c8 * c8 - s8 * s8; S16[nf] = 2.f * c8 * s8;
  }
  __syncthreads();

#pragma unroll
  for (int z = 0; z < 3; ++z) {
    f32x4 acc[2][2];
#pragma unroll
    for (int mf = 0; mf < 2; ++mf)
#pragma unroll
      for (int nf = 0; nf < 2; ++nf) acc[mf][nf] = (f32x4){0.f, 0.f, 0.f, 0.f};
#pragma unroll
    for (int ks = 0; ks < 16; ++ks) {
      const int off = (((ks * 4) + g) ^ (r & 7)) << 3;
      bf16x8 a0 = *(const bf16x8*)&Al[(wm * 32 + r) * 512 + off];
      bf16x8 a1 = *(const bf16x8*)&Al[(wm * 32 + 16 + r) * 512 + off];
      bf16x8 b0 = *(const bf16x8*)&Bl[(wn * 32 + r) * 512 + off];
      bf16x8 b1 = *(const bf16x8*)&Bl[(wn * 32 + 16 + r) * 512 + off];
      acc[0][0] = __builtin_amdgcn_mfma_f32_16x16x32_bf16(a0, b0, acc[0][0], 0, 0, 0);
      acc[0][1] = __builtin_amdgcn_mfma_f32_16x16x32_bf16(a0, b1, acc[0][1], 0, 0, 0);
      acc[1][0] = __builtin_amdgcn_mfma_f32_16x16x32_bf16(a1, b0, acc[1][0], 0, 0, 0);
      acc[1][1] = __builtin_amdgcn_mfma_f32_16x16x32_bf16(a1, b1, acc[1][1], 0, 0, 0);
    }
    __syncthreads();

    if (z < 2) {
#pragma unroll
      for (int i = 0; i < 16; ++i) {
        const int row = wave * 16 + i;
        stage_row(Wt + (size_t)(z + 1) * 262144 + (size_t)(nbase + row) * 512,
                  &Bl[row * 512], lane, row & 7);
      }
    }

    if (z == 2) {
#pragma unroll
      for (int nf = 0; nf < 2; ++nf) {
        const int nl = wn * 32 + nf * 16 + r;
#pragma unroll
        for (int mf = 0; mf < 2; ++mf)
#pragma unroll
          for (int i = 0; i < 4; ++i)
            T[nl][wm * 32 + mf * 16 + g * 4 + i] = f2bf(acc[mf][nf][i]);
      }
      __syncthreads();
      const int bb = mbase >> 11, posb = mbase & 2047;
#pragma unroll
      for (int p = 0; p < 2; ++p) {
        const int row = p * 32 + (tid >> 3);
        bf16x8 v = *(const bf16x8*)&T[row][(tid & 7) * 8];
        *(bf16x8*)&Vt[((size_t)bb * 512 + nbase + row) * 2048 + posb + (tid & 7) * 8] = v;
      }
    } else {
#pragma unroll
      for (int pl = 0; pl < 2; ++pl) {
        if (pl) __syncthreads();
#pragma unroll
        for (int nf = 0; nf < 2; ++nf) {
          const int nl = wn * 32 + nf * 16 + r;
          float cz = CZ[nf], sz = SZ[nf];
          const float c1 = C1[nf], s1 = S1[nf], c16 = C16[nf], s16 = S16[nf];
#pragma unroll
          for (int mf = 0; mf < 2; ++mf) {
            float cc = cz, ss = sz;
#pragma unroll
            for (int i = 0; i < 4; ++i) {
              const float f = pl ? ss : cc;
              T[wm * 32 + mf * 16 + g * 4 + i][nl] = f2bf(acc[mf][nf][i] * f);
              float nc = cc * c1 - ss * s1, ns = cc * s1 + ss * c1;
              cc = nc; ss = ns;
            }
            float zc = cz * c16 - sz * s16, zs = cz * s16 + sz * c16;
            cz = zc; sz = zs;
          }
        }
        __syncthreads();
        unsigned short* dst = (z == 0) ? (pl ? Qs : Qc) : (pl ? Ks : Kc);
#pragma unroll
        for (int p = 0; p < 2; ++p) {
          const int row = p * 32 + (tid >> 3);
          bf16x8 v = *(const bf16x8*)&T[row][(tid & 7) * 8];
          *(bf16x8*)&dst[(size_t)(mbase + row) * 512 + nbase + (tid & 7) * 8] = v;
        }
      }
      __syncthreads();
    }
  }
}

// ---------------- Stage 2: retention, m-tile 32, 2 blocks/CU, decay-banded (W=256) ----
// 256 threads, QBLK=16. Wave roles: mf = wave&1 (m-frag), im = wave>>1 (re|im chains).
// Klds single-buffered 64 KB -> 2 blocks/CU co-resident (TLP hides staging latency).
// Output pack (verified): im | re<<16.
__global__ __launch_bounds__(256, 2) void ret_kernel(
    const unsigned short* __restrict__ Qc, const unsigned short* __restrict__ Qs,
    const unsigned short* __restrict__ Kc, const unsigned short* __restrict__ Ks,
    const unsigned short* __restrict__ Vt, uint32_t* __restrict__ out)
{
  __shared__ unsigned short Klds[64 * 512];   // rows 0-31: Kc, 32-63: Ks (swz granules)
  __shared__ unsigned short Prl[16 * 40];
  __shared__ unsigned short Pil[16 * 40];

  const int bid = blockIdx.x;
  const int sid = ((bid & 7) << 6) + (bid >> 3);  // XCD chunk swizzle (bijective, 512=8*64)
  const int b = sid >> 7;
  const int qblk = 127 - (sid & 127);             // heavy-first
  const int q0 = qblk * 16;
  const int tid = threadIdx.x;
  const int wave = tid >> 6;
  const int lane = tid & 63;
  const int r = lane & 15;
  const int g = lane >> 4;
  const int mf = wave & 1;
  const int im = wave >> 1;
  const int sw = r & 7;

  // ---- Q-frags: 16q x 512h (c & s) in registers (best-effort; budget 256 VGPR) ----
  bf16x8 qa[16], qb[16];
  {
    const unsigned short* qcr = Qc + ((size_t)b * 2048 + q0 + r) * 512 + g * 8;
    const unsigned short* qsr = Qs + ((size_t)b * 2048 + q0 + r) * 512 + g * 8;
#pragma unroll
    for (int ks = 0; ks < 16; ++ks) {
      qa[ks] = *(const bf16x8*)(qcr + ks * 32);
      qb[ks] = *(const bf16x8*)(qsr + ks * 32);
    }
  }

  const int ntiles = ((q0 + 15) >> 5) + 1;
  const int t0 = (q0 >= 256) ? ((q0 - 256) >> 5) : 0;   // decay band start (32-grain)

  // ---- stage K(t0): 64 rows split across 4 waves ----
  {
    const size_t kbase = ((size_t)b * 2048 + (t0 << 5)) * 512;
#pragma unroll
    for (int i = 0; i < 16; ++i) {
      const int rid = wave * 16 + i;
      const int row = rid & 31;
      const unsigned short* src = ((rid < 32) ? Kc : Ks) + kbase + (size_t)row * 512;
      stage_row(src, &Klds[(size_t)rid * 512], lane, rid & 7);
    }
  }
  __syncthreads();

  f32x4 outre[8], outim[8];
#pragma unroll
  for (int c = 0; c < 8; ++c) {
    outre[c] = (f32x4){0.f, 0.f, 0.f, 0.f};
    outim[c] = (f32x4){0.f, 0.f, 0.f, 0.f};
  }

  for (int t = t0; t < ntiles; ++t) {
    const int m0 = t << 5;
    // ---- Phase A: QK from LDS (swizzled) + reg Q; 2 chains x 16 ks per wave ----
    f32x4 a0 = {0.f, 0.f, 0.f, 0.f};
    f32x4 a1 = {0.f, 0.f, 0.f, 0.f};
    const unsigned short* krow_c = &Klds[(mf * 16 + r) * 512];
    const unsigned short* krow_s = krow_c + 32 * 512;
#pragma unroll
    for (int ks = 0; ks < 16; ++ks) {
      const int off = (((ks * 4) + g) ^ sw) << 3;
      bf16x8 ka = *(const bf16x8*)(krow_c + off);
      bf16x8 kb = *(const bf16x8*)(krow_s + off);
      if (im == 0) {
        a0 = __builtin_amdgcn_mfma_f32_16x16x32_bf16(ka, qa[ks], a0, 0, 0, 0);  // cc
        a1 = __builtin_amdgcn_mfma_f32_16x16x32_bf16(kb, qb[ks], a1, 0, 0, 0);  // ss
      } else {
        a0 = __builtin_amdgcn_mfma_f32_16x16x32_bf16(ka, qb[ks], a0, 0, 0, 0);  // sc
        a1 = __builtin_amdgcn_mfma_f32_16x16x32_bf16(kb, qa[ks], a1, 0, 0, 0);  // cs
      }
    }
    // decay + pack P (r10-verified layout: P[q=r][m], stride 40)
    {
      const int qg = q0 + r;
      const int mg = m0 + mf * 16 + g * 4;
      ushort4 pk;
#pragma unroll
      for (int rg = 0; rg < 4; ++rg) {
        int d = qg - (mg + rg);
        float wdec = (d >= 0) ? exp2f((float)d * LOG2G) : 0.0f;
        float val = (im == 0) ? (a0[rg] + a1[rg]) : (a0[rg] - a1[rg]);
        ((unsigned short*)&pk)[rg] = f2bf(val * wdec);
      }
      unsigned short* dst = (im == 0) ? Prl : Pil;
      *(ushort4*)&dst[r * 40 + mf * 16 + g * 4] = pk;
    }
    __syncthreads();   // P visible; all waves done reading K(t)

    // ---- V loads FIRST (h-slice of 128 per wave; K=32 -> one frag per c) ----
    const unsigned short* vtp =
        Vt + ((size_t)b * 512 + wave * 128 + r) * 2048 + m0 + g * 8;
    bf16x8 vv[8];
#pragma unroll
    for (int c = 0; c < 8; ++c)
      vv[c] = *(const bf16x8*)(vtp + (size_t)c * 16 * 2048);

    // ---- issue K(t+1) staging (drains during PV) ----
    if (t + 1 < ntiles) {
      const size_t kbase = ((size_t)b * 2048 + m0 + 32) * 512;
#pragma unroll
      for (int i = 0; i < 16; ++i) {
        const int rid = wave * 16 + i;
        const int row = rid & 31;
        const unsigned short* src = ((rid < 32) ? Kc : Ks) + kbase + (size_t)row * 512;
        stage_row(src, &Klds[(size_t)rid * 512], lane, rid & 7);
      }
    }

    // ---- Phase B: out += P @ V ----
    {
      bf16x8 pr = *(const bf16x8*)&Prl[r * 40 + g * 8];
      bf16x8 pi = *(const bf16x8*)&Pil[r * 40 + g * 8];
#pragma unroll
      for (int c = 0; c < 8; ++c) {
        outre[c] = __builtin_amdgcn_mfma_f32_16x16x32_bf16(pr, vv[c], outre[c], 0, 0, 0);
        outim[c] = __builtin_amdgcn_mfma_f32_16x16x32_bf16(pi, vv[c], outim[c], 0, 0, 0);
      }
    }
    __syncthreads();   // drains staging (vmcnt 0) + P reuse safe
  }

  // epilogue: row q = q0 + g*4+rg, col h = wave*128 + c*16 + r; pack im | re<<16
#pragma unroll
  for (int c = 0; c < 8; ++c) {
#pragma unroll
    for (int rg = 0; rg < 4; ++rg) {
      const int q = q0 + g * 4 + rg;
      const int h = wave * 128 + c * 16 + r;
      const size_t o = ((size_t)b * 2048 + q) * 512 + h;
      out[o] = (uint32_t)f2bf(outim[c][rg]) | ((uint32_t)f2bf(outre[c][rg]) << 16);
    }
  }
}

extern "C" void kernel_launch(void* const* d_in, const int* in_sizes, int n_in,
                              void* d_out, int out_size, void* d_ws, size_t ws_size,
                              hipStream_t stream) {
  (void)in_sizes; (void)n_in; (void)out_size; (void)ws_size;
  const float* x     = (const float*)d_in[0];
  const float* wq    = (const float*)d_in[1];
  const float* wk    = (const float*)d_in[2];
  const float* wv    = (const float*)d_in[3];
  const float* theta = (const float*)d_in[4];

  const size_t NEL = (size_t)4 * 2048 * 512;   // elements per bf16 matrix
  unsigned short* Qc = (unsigned short*)d_ws;
  unsigned short* Qs = Qc + NEL;
  unsigned short* Kc = Qs + NEL;
  unsigned short* Ks = Kc + NEL;
  unsigned short* Vt = Ks + NEL;               // [B][H][S]
  // transient buffers in d_out (fully overwritten by ret_kernel afterwards)
  unsigned short* Wt = (unsigned short*)d_out;             // 1.5 MB
  unsigned short* xb = (unsigned short*)d_out + 2097152;   // 8.4 MB @ 4MB offset

  prep_kernel<<<192, 256, 0, stream>>>(wq, wk, wv, Wt);
  xconv_kernel<<<2048, 256, 0, stream>>>(x, xb);
  dim3 gp(8, 128);
  proj_kernel<<<gp, 256, 0, stream>>>(xb, Wt, theta, Qc, Qs, Kc, Ks, Vt);
  ret_kernel<<<512, 256, 0, stream>>>(Qc, Qs, Kc, Ks, Vt, (uint32_t*)d_out);
}

// Round 18
// 96.738 us; speedup vs baseline: 1.4636x; 1.4560x over previous
//
#include <hip/hip_runtime.h>
#include <stdint.h>

#define LOG2G -0.045803689611862786f   // log2(0.96875)

typedef float f32x4 __attribute__((ext_vector_type(4)));
typedef short bf16x8 __attribute__((ext_vector_type(8)));

__device__ inline unsigned short f2bf(float f) {
  uint32_t u = __builtin_bit_cast(uint32_t, f);
  u += 0x7FFFu + ((u >> 16) & 1u);     // RNE
  return (unsigned short)(u >> 16);
}
__device__ inline float b2f(unsigned short u) {
  return __builtin_bit_cast(float, (uint32_t)u << 16);
}

#if __has_builtin(__builtin_amdgcn_global_load_lds)
#define USE_GLL 1
#endif

// Stage one 1KB row (512 bf16) of global into LDS. Lane l covers granule l (16B).
__device__ __forceinline__ void stage_row(const unsigned short* __restrict__ srcrow,
                                          unsigned short* ldsrow, int lane, int swz) {
#ifdef USE_GLL
  __builtin_amdgcn_global_load_lds(
      (const __attribute__((address_space(1))) uint32_t*)((const char*)srcrow + ((lane ^ swz) << 4)),
      (__attribute__((address_space(3))) uint32_t*)ldsrow, 16, 0, 0);
#else
  bf16x8 v = *(const bf16x8*)((const char*)srcrow + ((lane ^ swz) << 4));
  *(bf16x8*)((char*)ldsrow + (lane << 4)) = v;
#endif
}

// ---------------- Stage 0a: transpose W -> Wt[n][k] bf16 ----------------
__global__ __launch_bounds__(256) void prep_kernel(
    const float* __restrict__ wq, const float* __restrict__ wk,
    const float* __restrict__ wv, unsigned short* __restrict__ Wt)
{
  __shared__ unsigned short lh[64][68];
  const int blk = blockIdx.x;
  const int w3 = blk >> 6;
  const int tile = blk & 63;
  const int tk = (tile >> 3) * 64, tn = (tile & 7) * 64;
  const float* W = (w3 == 0) ? wq : ((w3 == 1) ? wk : wv);
  const int t = threadIdx.x;
  {
    const int kl = t >> 2, nq = (t & 3) * 16;
#pragma unroll
    for (int f = 0; f < 4; ++f) {
      float4 v = *(const float4*)&W[(size_t)(tk + kl) * 512 + tn + nq + f * 4];
      float vv[4] = {v.x, v.y, v.z, v.w};
      ushort4 h4;
#pragma unroll
      for (int e = 0; e < 4; ++e) ((unsigned short*)&h4)[e] = f2bf(vv[e]);
      *(ushort4*)&lh[kl][nq + f * 4] = h4;
    }
  }
  __syncthreads();
  {
    const int nl = t >> 2, kq = (t & 3) * 16;
    unsigned short* outh = Wt + (size_t)w3 * 262144 + (size_t)(tn + nl) * 512 + tk + kq;
#pragma unroll
    for (int f = 0; f < 4; ++f) {
      ushort4 h4;
#pragma unroll
      for (int e = 0; e < 4; ++e) ((unsigned short*)&h4)[e] = lh[kq + f * 4 + e][nl];
      *(ushort4*)&outh[f * 4] = h4;
    }
  }
}

// ---------------- Stage 0b: x fp32 -> bf16 ----------------
__global__ __launch_bounds__(256) void xconv_kernel(
    const float* __restrict__ x, unsigned short* __restrict__ xb)
{
  const size_t i = ((size_t)blockIdx.x * 256 + threadIdx.x) * 8;
  float4 v0 = *(const float4*)&x[i];
  float4 v1 = *(const float4*)&x[i + 4];
  bf16x8 o;
  o[0] = (short)f2bf(v0.x); o[1] = (short)f2bf(v0.y);
  o[2] = (short)f2bf(v0.z); o[3] = (short)f2bf(v0.w);
  o[4] = (short)f2bf(v1.x); o[5] = (short)f2bf(v1.y);
  o[6] = (short)f2bf(v1.z); o[7] = (short)f2bf(v1.w);
  *(bf16x8*)&xb[i] = o;
}

// ---------------- Stage 1: LDS-staged MFMA projections (z-merged) ----------------
__global__ __launch_bounds__(256) void proj_kernel(
    const unsigned short* __restrict__ xb, const unsigned short* __restrict__ Wt,
    const float* __restrict__ theta,
    unsigned short* __restrict__ Qc, unsigned short* __restrict__ Qs,
    unsigned short* __restrict__ Kc, unsigned short* __restrict__ Ks,
    unsigned short* __restrict__ Vt)
{
  __shared__ unsigned short Al[64 * 512];   // 64 KB
  __shared__ unsigned short Bl[64 * 512];   // 64 KB
  __shared__ unsigned short T[64][136];     // 17.4 KB
  const int tid = threadIdx.x;
  const int wave = tid >> 6, lane = tid & 63;
  const int r = lane & 15, g = lane >> 4;
  const int wm = wave >> 1, wn = wave & 1;
  const int nbase = blockIdx.x * 64, mbase = blockIdx.y * 64;

#pragma unroll
  for (int i = 0; i < 16; ++i) {
    const int row = wave * 16 + i;
    stage_row(xb + (size_t)(mbase + row) * 512, &Al[row * 512], lane, row & 7);
  }
#pragma unroll
  for (int i = 0; i < 16; ++i) {
    const int row = wave * 16 + i;
    stage_row(Wt + (size_t)(nbase + row) * 512, &Bl[row * 512], lane, row & 7);
  }

  float C1[2], S1[2], CZ[2], SZ[2], C16[2], S16[2];
  const int pos0 = (mbase & 2047) + wm * 32 + g * 4;
#pragma unroll
  for (int nf = 0; nf < 2; ++nf) {
    const float th = theta[nbase + wn * 32 + nf * 16 + r];
    float c1, s1, cz, sz;
    sincosf(th, &s1, &c1);
    sincosf((float)(pos0 + 1) * th, &sz, &cz);
    float c2 = c1 * c1 - s1 * s1, s2 = 2.f * c1 * s1;
    float c4 = c2 * c2 - s2 * s2, s4 = 2.f * c2 * s2;
    float c8 = c4 * c4 - s4 * s4, s8 = 2.f * c4 * s4;
    C1[nf] = c1; S1[nf] = s1; CZ[nf] = cz; SZ[nf] = sz;
    C16[nf] = c8 * c8 - s8 * s8; S16[nf] = 2.f * c8 * s8;
  }
  __syncthreads();

#pragma unroll
  for (int z = 0; z < 3; ++z) {
    f32x4 acc[2][2];
#pragma unroll
    for (int mf = 0; mf < 2; ++mf)
#pragma unroll
      for (int nf = 0; nf < 2; ++nf) acc[mf][nf] = (f32x4){0.f, 0.f, 0.f, 0.f};
#pragma unroll
    for (int ks = 0; ks < 16; ++ks) {
      const int off = (((ks * 4) + g) ^ (r & 7)) << 3;
      bf16x8 a0 = *(const bf16x8*)&Al[(wm * 32 + r) * 512 + off];
      bf16x8 a1 = *(const bf16x8*)&Al[(wm * 32 + 16 + r) * 512 + off];
      bf16x8 b0 = *(const bf16x8*)&Bl[(wn * 32 + r) * 512 + off];
      bf16x8 b1 = *(const bf16x8*)&Bl[(wn * 32 + 16 + r) * 512 + off];
      acc[0][0] = __builtin_amdgcn_mfma_f32_16x16x32_bf16(a0, b0, acc[0][0], 0, 0, 0);
      acc[0][1] = __builtin_amdgcn_mfma_f32_16x16x32_bf16(a0, b1, acc[0][1], 0, 0, 0);
      acc[1][0] = __builtin_amdgcn_mfma_f32_16x16x32_bf16(a1, b0, acc[1][0], 0, 0, 0);
      acc[1][1] = __builtin_amdgcn_mfma_f32_16x16x32_bf16(a1, b1, acc[1][1], 0, 0, 0);
    }
    __syncthreads();

    if (z < 2) {
#pragma unroll
      for (int i = 0; i < 16; ++i) {
        const int row = wave * 16 + i;
        stage_row(Wt + (size_t)(z + 1) * 262144 + (size_t)(nbase + row) * 512,
                  &Bl[row * 512], lane, row & 7);
      }
    }

    if (z == 2) {
#pragma unroll
      for (int nf = 0; nf < 2; ++nf) {
        const int nl = wn * 32 + nf * 16 + r;
#pragma unroll
        for (int mf = 0; mf < 2; ++mf)
#pragma unroll
          for (int i = 0; i < 4; ++i)
            T[nl][wm * 32 + mf * 16 + g * 4 + i] = f2bf(acc[mf][nf][i]);
      }
      __syncthreads();
      const int bb = mbase >> 11, posb = mbase & 2047;
#pragma unroll
      for (int p = 0; p < 2; ++p) {
        const int row = p * 32 + (tid >> 3);
        bf16x8 v = *(const bf16x8*)&T[row][(tid & 7) * 8];
        *(bf16x8*)&Vt[((size_t)bb * 512 + nbase + row) * 2048 + posb + (tid & 7) * 8] = v;
      }
    } else {
#pragma unroll
      for (int pl = 0; pl < 2; ++pl) {
        if (pl) __syncthreads();
#pragma unroll
        for (int nf = 0; nf < 2; ++nf) {
          const int nl = wn * 32 + nf * 16 + r;
          float cz = CZ[nf], sz = SZ[nf];
          const float c1 = C1[nf], s1 = S1[nf], c16 = C16[nf], s16 = S16[nf];
#pragma unroll
          for (int mf = 0; mf < 2; ++mf) {
            float cc = cz, ss = sz;
#pragma unroll
            for (int i = 0; i < 4; ++i) {
              const float f = pl ? ss : cc;
              T[wm * 32 + mf * 16 + g * 4 + i][nl] = f2bf(acc[mf][nf][i] * f);
              float nc = cc * c1 - ss * s1, ns = cc * s1 + ss * c1;
              cc = nc; ss = ns;
            }
            float zc = cz * c16 - sz * s16, zs = cz * s16 + sz * c16;
            cz = zc; sz = zs;
          }
        }
        __syncthreads();
        unsigned short* dst = (z == 0) ? (pl ? Qs : Qc) : (pl ? Ks : Kc);
#pragma unroll
        for (int p = 0; p < 2; ++p) {
          const int row = p * 32 + (tid >> 3);
          bf16x8 v = *(const bf16x8*)&T[row][(tid & 7) * 8];
          *(bf16x8*)&dst[(size_t)(mbase + row) * 512 + nbase + (tid & 7) * 8] = v;
        }
      }
      __syncthreads();
    }
  }
}

// ---------------- Stage 2: retention, QBLK=32 via q-group waves, m-tile 32 ----------
// 256 threads, 4 waves, role (mf = wave&1 m-frag, wq = wave>>1 q-group). Q-in-regs per
// wave's own q-group (1 wave/SIMD -> full reg budget). 256 blocks = single round.
// Decay band W=256. Output pack (verified): im | re<<16.
__global__ __launch_bounds__(256, 1) void ret_kernel(
    const unsigned short* __restrict__ Qc, const unsigned short* __restrict__ Qs,
    const unsigned short* __restrict__ Kc, const unsigned short* __restrict__ Ks,
    const unsigned short* __restrict__ Vt, uint32_t* __restrict__ out)
{
  __shared__ unsigned short Klds[64 * 512];   // rows 0-31: Kc, 32-63: Ks (swz granules)
  __shared__ unsigned short Prl[2][16 * 40];
  __shared__ unsigned short Pil[2][16 * 40];

  const int bid = blockIdx.x;
  const int sid = ((bid & 7) << 5) + (bid >> 3);  // XCD chunk swizzle (bijective, 256=8*32)
  const int b = sid >> 6;
  const int qblk = 63 - (sid & 63);               // heavy-first
  const int q0 = qblk * 32;
  const int tid = threadIdx.x;
  const int wave = tid >> 6;
  const int lane = tid & 63;
  const int r = lane & 15;
  const int g = lane >> 4;
  const int mf = wave & 1;
  const int wq = wave >> 1;
  const int sw = r & 7;

  // ---- Q-frags: this wave's q-group rows (q0 + wq*16 + r) x 512h, c & s ----
  bf16x8 qa[16], qb[16];
  {
    const unsigned short* qcr = Qc + ((size_t)b * 2048 + q0 + wq * 16 + r) * 512 + g * 8;
    const unsigned short* qsr = Qs + ((size_t)b * 2048 + q0 + wq * 16 + r) * 512 + g * 8;
#pragma unroll
    for (int ks = 0; ks < 16; ++ks) {
      qa[ks] = *(const bf16x8*)(qcr + ks * 32);
      qb[ks] = *(const bf16x8*)(qsr + ks * 32);
    }
  }
#pragma unroll
  for (int ks = 0; ks < 16; ++ks)
    asm volatile("" : "+v"(qa[ks]), "+v"(qb[ks]));   // pin: forbid remat from global

  const int ntiles = ((q0 + 31) >> 5) + 1;
  const int t0 = (q0 >= 256) ? ((q0 - 256) >> 5) : 0;   // decay band start (32-grain)

  // ---- stage K(t0): 64 rows split across 4 waves ----
  {
    const size_t kbase = ((size_t)b * 2048 + (t0 << 5)) * 512;
#pragma unroll
    for (int i = 0; i < 16; ++i) {
      const int rid = wave * 16 + i;
      const int row = rid & 31;
      const unsigned short* src = ((rid < 32) ? Kc : Ks) + kbase + (size_t)row * 512;
      stage_row(src, &Klds[(size_t)rid * 512], lane, rid & 7);
    }
  }
  __syncthreads();

  f32x4 outre[2][8], outim[2][8];
#pragma unroll
  for (int qg = 0; qg < 2; ++qg)
#pragma unroll
    for (int c = 0; c < 8; ++c) {
      outre[qg][c] = (f32x4){0.f, 0.f, 0.f, 0.f};
      outim[qg][c] = (f32x4){0.f, 0.f, 0.f, 0.f};
    }

  for (int t = t0; t < ntiles; ++t) {
    const int m0 = t << 5;
    // ---- Phase A: QK (4 chains, own q-group) from LDS + reg Q ----
    f32x4 acc_cc = {0.f, 0.f, 0.f, 0.f};
    f32x4 acc_ss = {0.f, 0.f, 0.f, 0.f};
    f32x4 ai1 = {0.f, 0.f, 0.f, 0.f};
    f32x4 ai2 = {0.f, 0.f, 0.f, 0.f};
    const unsigned short* krow_c = &Klds[(mf * 16 + r) * 512];
    const unsigned short* krow_s = krow_c + 32 * 512;
#pragma unroll
    for (int ks = 0; ks < 16; ++ks) {
      const int off = (((ks * 4) + g) ^ sw) << 3;
      bf16x8 ka = *(const bf16x8*)(krow_c + off);
      bf16x8 kb = *(const bf16x8*)(krow_s + off);
      acc_cc = __builtin_amdgcn_mfma_f32_16x16x32_bf16(ka, qa[ks], acc_cc, 0, 0, 0);
      acc_ss = __builtin_amdgcn_mfma_f32_16x16x32_bf16(kb, qb[ks], acc_ss, 0, 0, 0);
      ai1    = __builtin_amdgcn_mfma_f32_16x16x32_bf16(ka, qb[ks], ai1, 0, 0, 0);
      ai2    = __builtin_amdgcn_mfma_f32_16x16x32_bf16(kb, qa[ks], ai2, 0, 0, 0);
    }
    // decay + pack P for (wq, mf).  P layout: row q=r, m = mf*16+g*4+rg, stride 40
    {
      const int qrow = q0 + wq * 16 + r;
      const int mg = m0 + mf * 16 + g * 4;
      ushort4 pkre, pkim;
#pragma unroll
      for (int rg = 0; rg < 4; ++rg) {
        int d = qrow - (mg + rg);
        float wdec = (d >= 0) ? exp2f((float)d * LOG2G) : 0.0f;
        ((unsigned short*)&pkre)[rg] = f2bf((acc_cc[rg] + acc_ss[rg]) * wdec);
        ((unsigned short*)&pkim)[rg] = f2bf((ai1[rg] - ai2[rg]) * wdec);
      }
      *(ushort4*)&Prl[wq][r * 40 + mf * 16 + g * 4] = pkre;
      *(ushort4*)&Pil[wq][r * 40 + mf * 16 + g * 4] = pkim;
    }
    __syncthreads();   // P visible; all waves done reading K(t)

    // ---- V loads FIRST (h-slice of 128 per wave; one frag per c at m-tile 32) ----
    const unsigned short* vtp =
        Vt + ((size_t)b * 512 + wave * 128 + r) * 2048 + m0 + g * 8;
    bf16x8 vv[8];
#pragma unroll
    for (int c = 0; c < 8; ++c)
      vv[c] = *(const bf16x8*)(vtp + (size_t)c * 16 * 2048);

    // ---- issue K(t+1) staging (drains during PV) ----
    if (t + 1 < ntiles) {
      const size_t kbase = ((size_t)b * 2048 + m0 + 32) * 512;
#pragma unroll
      for (int i = 0; i < 16; ++i) {
        const int rid = wave * 16 + i;
        const int row = rid & 31;
        const unsigned short* src = ((rid < 32) ? Kc : Ks) + kbase + (size_t)row * 512;
        stage_row(src, &Klds[(size_t)rid * 512], lane, rid & 7);
      }
    }

    // ---- Phase B: out += P @ V for both q-groups (vv shared) ----
#pragma unroll
    for (int qg = 0; qg < 2; ++qg) {
      bf16x8 pr = *(const bf16x8*)&Prl[qg][r * 40 + g * 8];
      bf16x8 pi = *(const bf16x8*)&Pil[qg][r * 40 + g * 8];
#pragma unroll
      for (int c = 0; c < 8; ++c) {
        outre[qg][c] = __builtin_amdgcn_mfma_f32_16x16x32_bf16(pr, vv[c], outre[qg][c], 0, 0, 0);
        outim[qg][c] = __builtin_amdgcn_mfma_f32_16x16x32_bf16(pi, vv[c], outim[qg][c], 0, 0, 0);
      }
    }
    __syncthreads();   // drains staging (vmcnt 0) + P reuse safe
  }

  // epilogue: row q = q0 + qg*16 + g*4+rg, col h = wave*128 + c*16 + r; pack im|re<<16
#pragma unroll
  for (int qg = 0; qg < 2; ++qg)
#pragma unroll
    for (int c = 0; c < 8; ++c)
#pragma unroll
      for (int rg = 0; rg < 4; ++rg) {
        const int q = q0 + qg * 16 + g * 4 + rg;
        const int h = wave * 128 + c * 16 + r;
        const size_t o = ((size_t)b * 2048 + q) * 512 + h;
        out[o] = (uint32_t)f2bf(outim[qg][c][rg]) | ((uint32_t)f2bf(outre[qg][c][rg]) << 16);
      }
}

extern "C" void kernel_launch(void* const* d_in, const int* in_sizes, int n_in,
                              void* d_out, int out_size, void* d_ws, size_t ws_size,
                              hipStream_t stream) {
  (void)in_sizes; (void)n_in; (void)out_size; (void)ws_size;
  const float* x     = (const float*)d_in[0];
  const float* wq    = (const float*)d_in[1];
  const float* wk    = (const float*)d_in[2];
  const float* wv    = (const float*)d_in[3];
  const float* theta = (const float*)d_in[4];

  const size_t NEL = (size_t)4 * 2048 * 512;   // elements per bf16 matrix
  unsigned short* Qc = (unsigned short*)d_ws;
  unsigned short* Qs = Qc + NEL;
  unsigned short* Kc = Qs + NEL;
  unsigned short* Ks = Kc + NEL;
  unsigned short* Vt = Ks + NEL;               // [B][H][S]
  // transient buffers in d_out (fully overwritten by ret_kernel afterwards)
  unsigned short* Wt = (unsigned short*)d_out;             // 1.5 MB
  unsigned short* xb = (unsigned short*)d_out + 2097152;   // 8.4 MB @ 4MB offset

  prep_kernel<<<192, 256, 0, stream>>>(wq, wk, wv, Wt);
  xconv_kernel<<<2048, 256, 0, stream>>>(x, xb);
  dim3 gp(8, 128);
  proj_kernel<<<gp, 256, 0, stream>>>(xb, Wt, theta, Qc, Qs, Kc, Ks, Vt);
  ret_kernel<<<256, 256, 0, stream>>>(Qc, Qs, Kc, Ks, Vt, (uint32_t*)d_out);
}